// Round 2
// baseline (10000.330 us; speedup 1.0000x reference)
//
#include <hip/hip_runtime.h>
#include <hip/hip_bf16.h>
#include <math.h>

// Problem constants
constexpr int Bb  = 16;
constexpr int Ss  = 2048;
constexpr int INd = 32;
constexpr int Dd  = 512;
constexpr int FFf = 2048;
constexpr int Ll  = 6;
constexpr int BS  = Bb * Ss;          // 32768 tokens
constexpr float EPSf = 1e-5f;

// ---------------------------------------------------------------------------
// Encoder: x[b,s,:] = (src[b,s,:] @ enc_w.T + enc_b) * sqrt(D) + pe[b,0,:]
// NOTE: reproduces the reference's pe[:x.shape[0]] broadcast (per-BATCH pe row)
// ---------------------------------------------------------------------------
__global__ __launch_bounds__(256)
void encode_kernel(const float* __restrict__ src, const float* __restrict__ pe,
                   const float* __restrict__ ew, const float* __restrict__ eb,
                   float* __restrict__ y) {
    __shared__ float srow[4][32];
    const int wv   = threadIdx.x >> 6;
    const int lane = threadIdx.x & 63;
    const int wid  = blockIdx.x * 4 + wv;        // token id
    const int b    = wid >> 11;                  // / 2048
    if (lane < 32) srow[wv][lane] = src[(size_t)wid * INd + lane];
    __syncthreads();
    const float sqrtD = 22.62741699796952f;
    const size_t obase = (size_t)wid * Dd;
    #pragma unroll
    for (int j = 0; j < 8; ++j) {
        const int d = j * 64 + lane;
        const float* wr = ew + d * INd;
        float acc = 0.f;
        #pragma unroll
        for (int k4 = 0; k4 < 8; ++k4) {
            float4 w4 = *(const float4*)(wr + k4 * 4);
            acc = fmaf(srow[wv][k4*4+0], w4.x, acc);
            acc = fmaf(srow[wv][k4*4+1], w4.y, acc);
            acc = fmaf(srow[wv][k4*4+2], w4.z, acc);
            acc = fmaf(srow[wv][k4*4+3], w4.w, acc);
        }
        y[obase + d] = (acc + eb[d]) * sqrtD + pe[(size_t)b * Dd + d];
    }
}

// ---------------------------------------------------------------------------
// Sparse window attention (W=3 -> 7 keys) + residual + LayerNorm, fused.
// One wave per token. Lane l owns dims [l*4, l*4+4) and [256+l*4, 256+l*4+4).
// ---------------------------------------------------------------------------
__global__ __launch_bounds__(256)
void attn_ln_kernel(const float* __restrict__ x, float* __restrict__ y,
                    const float* __restrict__ g, const float* __restrict__ bb) {
    const int wv   = threadIdx.x >> 6;
    const int lane = threadIdx.x & 63;
    const int wid  = blockIdx.x * 4 + wv;
    const int b    = wid >> 11;
    const int s    = wid & (Ss - 1);
    const float* base = x + (size_t)b * Ss * Dd;

    float rows[7][8];
    #pragma unroll
    for (int o = 0; o < 7; ++o) {
        int sp = s + o - 3;
        int sc = sp < 0 ? 0 : (sp > Ss - 1 ? Ss - 1 : sp);
        const float* r = base + (size_t)sc * Dd;
        float4 v0 = *(const float4*)(r + lane * 4);
        float4 v1 = *(const float4*)(r + 256 + lane * 4);
        rows[o][0] = v0.x; rows[o][1] = v0.y; rows[o][2] = v0.z; rows[o][3] = v0.w;
        rows[o][4] = v1.x; rows[o][5] = v1.y; rows[o][6] = v1.z; rows[o][7] = v1.w;
    }

    const float scale = 0.04419417382415922f;   // 1/sqrt(512)
    float score[7];
    #pragma unroll
    for (int o = 0; o < 7; ++o) {
        float p = 0.f;
        #pragma unroll
        for (int j = 0; j < 8; ++j) p = fmaf(rows[3][j], rows[o][j], p);
        #pragma unroll
        for (int m = 1; m < 64; m <<= 1) p += __shfl_xor(p, m, 64);
        int sp = s + o - 3;
        score[o] = (sp >= 0 && sp < Ss) ? p * scale : -1e9f;
    }
    float mx = score[0];
    #pragma unroll
    for (int o = 1; o < 7; ++o) mx = fmaxf(mx, score[o]);
    float w[7], wsum = 0.f;
    #pragma unroll
    for (int o = 0; o < 7; ++o) { w[o] = __expf(score[o] - mx); wsum += w[o]; }
    const float inv = 1.f / wsum;
    #pragma unroll
    for (int o = 0; o < 7; ++o) w[o] *= inv;

    float r2[8];
    #pragma unroll
    for (int j = 0; j < 8; ++j) {
        float acc = rows[3][j];                 // residual (pre-LN x)
        #pragma unroll
        for (int o = 0; o < 7; ++o) acc = fmaf(w[o], rows[o][j], acc);
        r2[j] = acc;
    }

    // LayerNorm over 512
    float sm = 0.f, sq = 0.f;
    #pragma unroll
    for (int j = 0; j < 8; ++j) { sm += r2[j]; sq = fmaf(r2[j], r2[j], sq); }
    #pragma unroll
    for (int m = 1; m < 64; m <<= 1) {
        sm += __shfl_xor(sm, m, 64);
        sq += __shfl_xor(sq, m, 64);
    }
    const float mu   = sm * (1.f / Dd);
    const float var  = sq * (1.f / Dd) - mu * mu;
    const float rstd = rsqrtf(var + EPSf);

    const size_t ob = (size_t)wid * Dd;
    float4 g0 = *(const float4*)(g  + lane * 4);
    float4 b0 = *(const float4*)(bb + lane * 4);
    float4 g1 = *(const float4*)(g  + 256 + lane * 4);
    float4 b1 = *(const float4*)(bb + 256 + lane * 4);
    float4 o0, o1;
    o0.x = (r2[0] - mu) * rstd * g0.x + b0.x;
    o0.y = (r2[1] - mu) * rstd * g0.y + b0.y;
    o0.z = (r2[2] - mu) * rstd * g0.z + b0.z;
    o0.w = (r2[3] - mu) * rstd * g0.w + b0.w;
    o1.x = (r2[4] - mu) * rstd * g1.x + b1.x;
    o1.y = (r2[5] - mu) * rstd * g1.y + b1.y;
    o1.z = (r2[6] - mu) * rstd * g1.z + b1.z;
    o1.w = (r2[7] - mu) * rstd * g1.w + b1.w;
    *(float4*)(y + ob + lane * 4)       = o0;
    *(float4*)(y + ob + 256 + lane * 4) = o1;
}

// ---------------------------------------------------------------------------
// residual add + LayerNorm:  f <- LN(xres + f) * g + b   (in-place on f)
// ---------------------------------------------------------------------------
__global__ __launch_bounds__(256)
void add_ln_kernel(const float* __restrict__ xres, float* __restrict__ f,
                   const float* __restrict__ g, const float* __restrict__ bb) {
    const int wv   = threadIdx.x >> 6;
    const int lane = threadIdx.x & 63;
    const int wid  = blockIdx.x * 4 + wv;
    const size_t ob = (size_t)wid * Dd;

    float4 a0 = *(const float4*)(xres + ob + lane * 4);
    float4 f0 = *(const float4*)(f    + ob + lane * 4);
    float4 a1 = *(const float4*)(xres + ob + 256 + lane * 4);
    float4 f1 = *(const float4*)(f    + ob + 256 + lane * 4);
    float r2[8];
    r2[0] = a0.x + f0.x; r2[1] = a0.y + f0.y; r2[2] = a0.z + f0.z; r2[3] = a0.w + f0.w;
    r2[4] = a1.x + f1.x; r2[5] = a1.y + f1.y; r2[6] = a1.z + f1.z; r2[7] = a1.w + f1.w;

    float sm = 0.f, sq = 0.f;
    #pragma unroll
    for (int j = 0; j < 8; ++j) { sm += r2[j]; sq = fmaf(r2[j], r2[j], sq); }
    #pragma unroll
    for (int m = 1; m < 64; m <<= 1) {
        sm += __shfl_xor(sm, m, 64);
        sq += __shfl_xor(sq, m, 64);
    }
    const float mu   = sm * (1.f / Dd);
    const float var  = sq * (1.f / Dd) - mu * mu;
    const float rstd = rsqrtf(var + EPSf);

    float4 g0 = *(const float4*)(g  + lane * 4);
    float4 b0 = *(const float4*)(bb + lane * 4);
    float4 g1 = *(const float4*)(g  + 256 + lane * 4);
    float4 b1 = *(const float4*)(bb + 256 + lane * 4);
    float4 o0, o1;
    o0.x = (r2[0] - mu) * rstd * g0.x + b0.x;
    o0.y = (r2[1] - mu) * rstd * g0.y + b0.y;
    o0.z = (r2[2] - mu) * rstd * g0.z + b0.z;
    o0.w = (r2[3] - mu) * rstd * g0.w + b0.w;
    o1.x = (r2[4] - mu) * rstd * g1.x + b1.x;
    o1.y = (r2[5] - mu) * rstd * g1.y + b1.y;
    o1.z = (r2[6] - mu) * rstd * g1.z + b1.z;
    o1.w = (r2[7] - mu) * rstd * g1.w + b1.w;
    *(float4*)(f + ob + lane * 4)       = o0;
    *(float4*)(f + ob + 256 + lane * 4) = o1;
}

// ---------------------------------------------------------------------------
// fp32 NT GEMM:  C[m,n] = sum_k A[m,k]*B[n,k] + bias[n]   (optional ReLU)
// A: MxK row-major, B: NxK row-major. 128x128 tile, BK=32, 8x8 microtile.
// ---------------------------------------------------------------------------
constexpr int BM = 128, BN = 128, BK = 32, PAD = 4;

template<int RELU>
__global__ __launch_bounds__(256)
void gemm_nt(const float* __restrict__ A, const float* __restrict__ B,
             const float* __restrict__ bias, float* __restrict__ C,
             int M, int N, int K) {
    __shared__ float As[BK][BM + PAD];
    __shared__ float Bs[BK][BN + PAD];
    const int tid = threadIdx.x;
    const int tx  = tid & 15;
    const int ty  = tid >> 4;
    const size_t bm = (size_t)blockIdx.y * BM;
    const size_t bn = (size_t)blockIdx.x * BN;

    float acc[8][8];
    #pragma unroll
    for (int i = 0; i < 8; ++i)
        #pragma unroll
        for (int j = 0; j < 8; ++j) acc[i][j] = 0.f;

    const float* Ap = A + bm * K;
    const float* Bp = B + bn * K;

    for (int k0 = 0; k0 < K; k0 += BK) {
        #pragma unroll
        for (int i = 0; i < 4; ++i) {
            int li = tid + i * 256;
            int m  = li >> 3;
            int kq = li & 7;
            float4 v = *(const float4*)(Ap + (size_t)m * K + k0 + kq * 4);
            As[kq*4+0][m] = v.x; As[kq*4+1][m] = v.y;
            As[kq*4+2][m] = v.z; As[kq*4+3][m] = v.w;
        }
        #pragma unroll
        for (int i = 0; i < 4; ++i) {
            int li = tid + i * 256;
            int n  = li >> 3;
            int kq = li & 7;
            float4 v = *(const float4*)(Bp + (size_t)n * K + k0 + kq * 4);
            Bs[kq*4+0][n] = v.x; Bs[kq*4+1][n] = v.y;
            Bs[kq*4+2][n] = v.z; Bs[kq*4+3][n] = v.w;
        }
        __syncthreads();
        #pragma unroll
        for (int kk = 0; kk < BK; ++kk) {
            float a[8], bv[8];
            *(float4*)(a)      = *(const float4*)&As[kk][ty * 8];
            *(float4*)(a + 4)  = *(const float4*)&As[kk][ty * 8 + 4];
            *(float4*)(bv)     = *(const float4*)&Bs[kk][tx * 8];
            *(float4*)(bv + 4) = *(const float4*)&Bs[kk][tx * 8 + 4];
            #pragma unroll
            for (int i = 0; i < 8; ++i)
                #pragma unroll
                for (int j = 0; j < 8; ++j)
                    acc[i][j] = fmaf(a[i], bv[j], acc[i][j]);
        }
        __syncthreads();
    }

    #pragma unroll
    for (int i = 0; i < 8; ++i) {
        size_t m = bm + ty * 8 + i;
        #pragma unroll
        for (int j = 0; j < 8; j += 4) {
            int n = (int)bn + tx * 8 + j;
            float4 v;
            v.x = acc[i][j+0] + bias[n+0];
            v.y = acc[i][j+1] + bias[n+1];
            v.z = acc[i][j+2] + bias[n+2];
            v.w = acc[i][j+3] + bias[n+3];
            if (RELU) {
                v.x = fmaxf(v.x, 0.f); v.y = fmaxf(v.y, 0.f);
                v.z = fmaxf(v.z, 0.f); v.w = fmaxf(v.w, 0.f);
            }
            *(float4*)(C + m * N + n) = v;
        }
    }
}

// ---------------------------------------------------------------------------
// Decoder: out[b] = x[b, S-1, :] . dec_w + dec_b
// ---------------------------------------------------------------------------
__global__ __launch_bounds__(64)
void decode_kernel(const float* __restrict__ x, const float* __restrict__ dw,
                   const float* __restrict__ db, float* __restrict__ out) {
    const int b = blockIdx.x;
    const int lane = threadIdx.x;
    const float* r = x + ((size_t)b * Ss + (Ss - 1)) * Dd;
    float acc = 0.f;
    #pragma unroll
    for (int j = 0; j < 8; ++j) acc = fmaf(r[j*64 + lane], dw[j*64 + lane], acc);
    #pragma unroll
    for (int m = 1; m < 64; m <<= 1) acc += __shfl_xor(acc, m, 64);
    if (lane == 0) out[b] = acc + db[0];
}

// ---------------------------------------------------------------------------
extern "C" void kernel_launch(void* const* d_in, const int* in_sizes, int n_in,
                              void* d_out, int out_size, void* d_ws, size_t ws_size,
                              hipStream_t stream) {
    const float* src   = (const float*)d_in[0];
    const float* pe    = (const float*)d_in[1];
    const float* enc_w = (const float*)d_in[2];
    const float* enc_b = (const float*)d_in[3];
    const float* l1_w  = (const float*)d_in[4];
    const float* l1_b  = (const float*)d_in[5];
    const float* l2_w  = (const float*)d_in[6];
    const float* l2_b  = (const float*)d_in[7];
    const float* n1_g  = (const float*)d_in[8];
    const float* n1_b  = (const float*)d_in[9];
    const float* n2_g  = (const float*)d_in[10];
    const float* n2_b  = (const float*)d_in[11];
    const float* dec_w = (const float*)d_in[12];
    const float* dec_b = (const float*)d_in[13];
    float* out = (float*)d_out;

    // workspace layout: xA (64MB) | xB (64MB) | h (chunk-sized, adapts to
    // ws_size).  With ws_size >= 384MB this is a single full-size h pass;
    // smaller workspaces run the FFN in row-chunks (min 128 rows = 1MB).
    float* xA = (float*)d_ws;
    float* xB = xA + (size_t)BS * Dd;
    float* h  = xB + (size_t)BS * Dd;

    const size_t fixedBytes = (size_t)2 * BS * Dd * sizeof(float);   // 128MB
    size_t hBytes   = ws_size > fixedBytes ? ws_size - fixedBytes : 0;
    int    chunkM   = (int)(hBytes / ((size_t)FFf * sizeof(float)));
    if (chunkM > BS) chunkM = BS;
    chunkM &= ~(BM - 1);                 // multiple of the GEMM tile height
    if (chunkM < BM) chunkM = BM;        // last resort: 1MB chunk

    encode_kernel<<<BS / 4, 256, 0, stream>>>(src, pe, enc_w, enc_b, xA);

    for (int i = 0; i < Ll; ++i) {
        attn_ln_kernel<<<BS / 4, 256, 0, stream>>>(
            xA, xB, n1_g + i * Dd, n1_b + i * Dd);
        for (int m0 = 0; m0 < BS; m0 += chunkM) {
            int mh = (BS - m0) < chunkM ? (BS - m0) : chunkM;
            gemm_nt<1><<<dim3(FFf / BN, mh / BM), 256, 0, stream>>>(
                xB + (size_t)m0 * Dd, l1_w + (size_t)i * FFf * Dd,
                l1_b + i * FFf, h, mh, FFf, Dd);
            gemm_nt<0><<<dim3(Dd / BN, mh / BM), 256, 0, stream>>>(
                h, l2_w + (size_t)i * Dd * FFf, l2_b + i * Dd,
                xA + (size_t)m0 * Dd, mh, Dd, FFf);
        }
        add_ln_kernel<<<BS / 4, 256, 0, stream>>>(
            xB, xA, n2_g + i * Dd, n2_b + i * Dd);
    }

    decode_kernel<<<Bb, 64, 0, stream>>>(xA, dec_w, dec_b, out);
}

// Round 8
// 2269.656 us; speedup vs baseline: 4.4061x; 4.4061x over previous
//
#include <hip/hip_runtime.h>
#include <hip/hip_bf16.h>
#include <math.h>

// Problem constants
constexpr int Bb  = 16;
constexpr int Ss  = 2048;
constexpr int INd = 32;
constexpr int Dd  = 512;
constexpr int FFf = 2048;
constexpr int Ll  = 6;
constexpr int BS  = Bb * Ss;          // 32768 tokens
constexpr float EPSf = 1e-5f;

typedef __attribute__((ext_vector_type(8))) short short8;   // 8 bf16 (4 VGPRs)
typedef __attribute__((ext_vector_type(4))) float f32x4;

__device__ __forceinline__ ushort f2bf(float f) {
    uint u = __float_as_uint(f);
    uint r = (u + 0x7fffu + ((u >> 16) & 1u)) >> 16;        // round-nearest-even
    return (ushort)r;
}

// ---------------------------------------------------------------------------
// fp32 -> bf16 bulk convert (weights, once per launch)
// ---------------------------------------------------------------------------
__global__ __launch_bounds__(256)
void convert_bf16(const float* __restrict__ in, ushort* __restrict__ out, int n4) {
    int i = blockIdx.x * blockDim.x + threadIdx.x;
    int stride = gridDim.x * blockDim.x;
    for (; i < n4; i += stride) {
        float4 v = ((const float4*)in)[i];
        ushort4 o;
        o.x = f2bf(v.x); o.y = f2bf(v.y); o.z = f2bf(v.z); o.w = f2bf(v.w);
        ((ushort4*)out)[i] = o;
    }
}

// ---------------------------------------------------------------------------
// Encoder: x[b,s,:] = (src[b,s,:] @ enc_w.T + enc_b) * sqrt(D) + pe[b,0,:]
// NOTE: reproduces the reference's pe[:x.shape[0]] broadcast (per-BATCH pe row)
// ---------------------------------------------------------------------------
__global__ __launch_bounds__(256)
void encode_kernel(const float* __restrict__ src, const float* __restrict__ pe,
                   const float* __restrict__ ew, const float* __restrict__ eb,
                   float* __restrict__ y) {
    __shared__ float srow[4][32];
    const int wv   = threadIdx.x >> 6;
    const int lane = threadIdx.x & 63;
    const int wid  = blockIdx.x * 4 + wv;        // token id
    const int b    = wid >> 11;                  // / 2048
    if (lane < 32) srow[wv][lane] = src[(size_t)wid * INd + lane];
    __syncthreads();
    const float sqrtD = 22.62741699796952f;
    const size_t obase = (size_t)wid * Dd;
    #pragma unroll
    for (int j = 0; j < 8; ++j) {
        const int d = j * 64 + lane;
        const float* wr = ew + d * INd;
        float acc = 0.f;
        #pragma unroll
        for (int k4 = 0; k4 < 8; ++k4) {
            float4 w4 = *(const float4*)(wr + k4 * 4);
            acc = fmaf(srow[wv][k4*4+0], w4.x, acc);
            acc = fmaf(srow[wv][k4*4+1], w4.y, acc);
            acc = fmaf(srow[wv][k4*4+2], w4.z, acc);
            acc = fmaf(srow[wv][k4*4+3], w4.w, acc);
        }
        y[obase + d] = (acc + eb[d]) * sqrtD + pe[(size_t)b * Dd + d];
    }
}

// ---------------------------------------------------------------------------
// Sparse window attention (W=3 -> 7 keys) + residual + LayerNorm, fused.
// One wave per token. Writes fp32 y (residual stream) AND bf16 ybf (GEMM1 A).
// ---------------------------------------------------------------------------
__global__ __launch_bounds__(256)
void attn_ln_kernel(const float* __restrict__ x, float* __restrict__ y,
                    ushort* __restrict__ ybf,
                    const float* __restrict__ g, const float* __restrict__ bb) {
    const int wv   = threadIdx.x >> 6;
    const int lane = threadIdx.x & 63;
    const int wid  = blockIdx.x * 4 + wv;
    const int b    = wid >> 11;
    const int s    = wid & (Ss - 1);
    const float* base = x + (size_t)b * Ss * Dd;

    float rows[7][8];
    #pragma unroll
    for (int o = 0; o < 7; ++o) {
        int sp = s + o - 3;
        int sc = sp < 0 ? 0 : (sp > Ss - 1 ? Ss - 1 : sp);
        const float* r = base + (size_t)sc * Dd;
        float4 v0 = *(const float4*)(r + lane * 4);
        float4 v1 = *(const float4*)(r + 256 + lane * 4);
        rows[o][0] = v0.x; rows[o][1] = v0.y; rows[o][2] = v0.z; rows[o][3] = v0.w;
        rows[o][4] = v1.x; rows[o][5] = v1.y; rows[o][6] = v1.z; rows[o][7] = v1.w;
    }

    const float scale = 0.04419417382415922f;   // 1/sqrt(512)
    float score[7];
    #pragma unroll
    for (int o = 0; o < 7; ++o) {
        float p = 0.f;
        #pragma unroll
        for (int j = 0; j < 8; ++j) p = fmaf(rows[3][j], rows[o][j], p);
        #pragma unroll
        for (int m = 1; m < 64; m <<= 1) p += __shfl_xor(p, m, 64);
        int sp = s + o - 3;
        score[o] = (sp >= 0 && sp < Ss) ? p * scale : -1e9f;
    }
    float mx = score[0];
    #pragma unroll
    for (int o = 1; o < 7; ++o) mx = fmaxf(mx, score[o]);
    float w[7], wsum = 0.f;
    #pragma unroll
    for (int o = 0; o < 7; ++o) { w[o] = __expf(score[o] - mx); wsum += w[o]; }
    const float inv = 1.f / wsum;
    #pragma unroll
    for (int o = 0; o < 7; ++o) w[o] *= inv;

    float r2[8];
    #pragma unroll
    for (int j = 0; j < 8; ++j) {
        float acc = rows[3][j];                 // residual (pre-LN x)
        #pragma unroll
        for (int o = 0; o < 7; ++o) acc = fmaf(w[o], rows[o][j], acc);
        r2[j] = acc;
    }

    // LayerNorm over 512
    float sm = 0.f, sq = 0.f;
    #pragma unroll
    for (int j = 0; j < 8; ++j) { sm += r2[j]; sq = fmaf(r2[j], r2[j], sq); }
    #pragma unroll
    for (int m = 1; m < 64; m <<= 1) {
        sm += __shfl_xor(sm, m, 64);
        sq += __shfl_xor(sq, m, 64);
    }
    const float mu   = sm * (1.f / Dd);
    const float var  = sq * (1.f / Dd) - mu * mu;
    const float rstd = rsqrtf(var + EPSf);

    const size_t ob = (size_t)wid * Dd;
    float4 g0 = *(const float4*)(g  + lane * 4);
    float4 b0 = *(const float4*)(bb + lane * 4);
    float4 g1 = *(const float4*)(g  + 256 + lane * 4);
    float4 b1 = *(const float4*)(bb + 256 + lane * 4);
    float4 o0, o1;
    o0.x = (r2[0] - mu) * rstd * g0.x + b0.x;
    o0.y = (r2[1] - mu) * rstd * g0.y + b0.y;
    o0.z = (r2[2] - mu) * rstd * g0.z + b0.z;
    o0.w = (r2[3] - mu) * rstd * g0.w + b0.w;
    o1.x = (r2[4] - mu) * rstd * g1.x + b1.x;
    o1.y = (r2[5] - mu) * rstd * g1.y + b1.y;
    o1.z = (r2[6] - mu) * rstd * g1.z + b1.z;
    o1.w = (r2[7] - mu) * rstd * g1.w + b1.w;
    *(float4*)(y + ob + lane * 4)       = o0;
    *(float4*)(y + ob + 256 + lane * 4) = o1;

    ushort4 q0, q1;
    q0.x = f2bf(o0.x); q0.y = f2bf(o0.y); q0.z = f2bf(o0.z); q0.w = f2bf(o0.w);
    q1.x = f2bf(o1.x); q1.y = f2bf(o1.y); q1.z = f2bf(o1.z); q1.w = f2bf(o1.w);
    *(ushort4*)(ybf + ob + lane * 4)       = q0;
    *(ushort4*)(ybf + ob + 256 + lane * 4) = q1;
}

// ---------------------------------------------------------------------------
// residual add + LayerNorm:  f <- LN(xres + f) * g + b   (in-place on f)
// ---------------------------------------------------------------------------
__global__ __launch_bounds__(256)
void add_ln_kernel(const float* __restrict__ xres, float* __restrict__ f,
                   const float* __restrict__ g, const float* __restrict__ bb) {
    const int wv   = threadIdx.x >> 6;
    const int lane = threadIdx.x & 63;
    const int wid  = blockIdx.x * 4 + wv;
    const size_t ob = (size_t)wid * Dd;

    float4 a0 = *(const float4*)(xres + ob + lane * 4);
    float4 f0 = *(const float4*)(f    + ob + lane * 4);
    float4 a1 = *(const float4*)(xres + ob + 256 + lane * 4);
    float4 f1 = *(const float4*)(f    + ob + 256 + lane * 4);
    float r2[8];
    r2[0] = a0.x + f0.x; r2[1] = a0.y + f0.y; r2[2] = a0.z + f0.z; r2[3] = a0.w + f0.w;
    r2[4] = a1.x + f1.x; r2[5] = a1.y + f1.y; r2[6] = a1.z + f1.z; r2[7] = a1.w + f1.w;

    float sm = 0.f, sq = 0.f;
    #pragma unroll
    for (int j = 0; j < 8; ++j) { sm += r2[j]; sq = fmaf(r2[j], r2[j], sq); }
    #pragma unroll
    for (int m = 1; m < 64; m <<= 1) {
        sm += __shfl_xor(sm, m, 64);
        sq += __shfl_xor(sq, m, 64);
    }
    const float mu   = sm * (1.f / Dd);
    const float var  = sq * (1.f / Dd) - mu * mu;
    const float rstd = rsqrtf(var + EPSf);

    float4 g0 = *(const float4*)(g  + lane * 4);
    float4 b0 = *(const float4*)(bb + lane * 4);
    float4 g1 = *(const float4*)(g  + 256 + lane * 4);
    float4 b1 = *(const float4*)(bb + 256 + lane * 4);
    float4 o0, o1;
    o0.x = (r2[0] - mu) * rstd * g0.x + b0.x;
    o0.y = (r2[1] - mu) * rstd * g0.y + b0.y;
    o0.z = (r2[2] - mu) * rstd * g0.z + b0.z;
    o0.w = (r2[3] - mu) * rstd * g0.w + b0.w;
    o1.x = (r2[4] - mu) * rstd * g1.x + b1.x;
    o1.y = (r2[5] - mu) * rstd * g1.y + b1.y;
    o1.z = (r2[6] - mu) * rstd * g1.z + b1.z;
    o1.w = (r2[7] - mu) * rstd * g1.w + b1.w;
    *(float4*)(f + ob + lane * 4)       = o0;
    *(float4*)(f + ob + 256 + lane * 4) = o1;
}

// ---------------------------------------------------------------------------
// bf16 MFMA NT GEMM (m97 structure): C[m,n] = sum_k A[m,k]*B[n,k] + bias[n]
// A: MxK bf16 row-major, B: NxK bf16 row-major. 128x128 tile, BK=32.
// 4 waves, each computes a 64x64 quadrant as 4x4 fragments of 16x16x32 MFMA.
// Staging via global_load_lds width=16 (wave-uniform LDS base + lane*16).
// Epilogue: +bias, optional ReLU, output fp32 or bf16.
// ---------------------------------------------------------------------------
template<int RELU, int BF16OUT>
__global__ __launch_bounds__(256)
void gemm_bf16(const ushort* __restrict__ A, const ushort* __restrict__ B,
               const float* __restrict__ bias, void* __restrict__ Cout,
               int M, int N, int K) {
    __shared__ ushort As[128 * 32];          // [row][k] bf16, 8KB
    __shared__ ushort Bs[128 * 32];
    const int tid  = threadIdx.x;
    const int wid  = tid >> 6;
    const int lane = tid & 63;
    const int wr   = wid >> 1;               // wave quadrant row (0/1)
    const int wc   = wid & 1;                // wave quadrant col (0/1)
    const size_t bm = (size_t)blockIdx.y * 128;
    const size_t bn = (size_t)blockIdx.x * 128;

    // staging sources: wave w stages rows [w*32, w*32+32) of the 128-row tile
    // each GLDS covers 16 rows; lane l -> row += (l>>2), k = (l&3)*8
    const ushort* gA0 = A + (bm + wid * 32 + (lane >> 2)) * (size_t)K + (lane & 3) * 8;
    const ushort* gA1 = gA0 + (size_t)16 * K;
    const ushort* gB0 = B + (bn + wid * 32 + (lane >> 2)) * (size_t)K + (lane & 3) * 8;
    const ushort* gB1 = gB0 + (size_t)16 * K;
    ushort* lA0 = &As[wid * 1024];           // (w*32 rows)*32 k
    ushort* lA1 = lA0 + 512;                 // +16 rows
    ushort* lB0 = &Bs[wid * 1024];
    ushort* lB1 = lB0 + 512;

    // fragment read bases: row = quadrant*64 + mt*16 + (lane&15), kg = lane>>4
    const ushort* aPtr = &As[(wr * 64 + (lane & 15)) * 32 + (lane >> 4) * 8];
    const ushort* bPtr = &Bs[(wc * 64 + (lane & 15)) * 32 + (lane >> 4) * 8];

    f32x4 acc[4][4];
    #pragma unroll
    for (int i = 0; i < 4; ++i)
        #pragma unroll
        for (int j = 0; j < 4; ++j) acc[i][j] = (f32x4){0.f, 0.f, 0.f, 0.f};

    #define GLDS(gp, lp) __builtin_amdgcn_global_load_lds( \
        (const __attribute__((address_space(1))) void*)(gp), \
        (__attribute__((address_space(3))) void*)(lp), 16, 0, 0)

    for (int k0 = 0; k0 < K; k0 += 32) {
        GLDS(gA0 + k0, lA0);
        GLDS(gA1 + k0, lA1);
        GLDS(gB0 + k0, lB0);
        GLDS(gB1 + k0, lB1);
        __syncthreads();
        short8 af[4], bf_[4];
        #pragma unroll
        for (int mt = 0; mt < 4; ++mt) af[mt]  = *(const short8*)(aPtr + mt * 512);
        #pragma unroll
        for (int nt = 0; nt < 4; ++nt) bf_[nt] = *(const short8*)(bPtr + nt * 512);
        #pragma unroll
        for (int mt = 0; mt < 4; ++mt)
            #pragma unroll
            for (int nt = 0; nt < 4; ++nt)
                acc[mt][nt] = __builtin_amdgcn_mfma_f32_16x16x32_bf16(
                    af[mt], bf_[nt], acc[mt][nt], 0, 0, 0);
        __syncthreads();
    }
    #undef GLDS

    // epilogue: C row = bm + wr*64 + mt*16 + (lane>>4)*4 + r ; col = bn + wc*64 + nt*16 + (lane&15)
    float* Cf  = (float*)Cout;
    ushort* Cb = (ushort*)Cout;
    #pragma unroll
    for (int nt = 0; nt < 4; ++nt) {
        const int cn = (int)bn + wc * 64 + nt * 16 + (lane & 15);
        const float bv = bias[cn];
        #pragma unroll
        for (int mt = 0; mt < 4; ++mt) {
            const size_t rowb = bm + wr * 64 + mt * 16 + (lane >> 4) * 4;
            #pragma unroll
            for (int r = 0; r < 4; ++r) {
                float v = acc[mt][nt][r] + bv;
                if (RELU) v = fmaxf(v, 0.f);
                if (BF16OUT) Cb[(rowb + r) * (size_t)N + cn] = f2bf(v);
                else         Cf[(rowb + r) * (size_t)N + cn] = v;
            }
        }
    }
}

// ---------------------------------------------------------------------------
// Decoder: out[b] = x[b, S-1, :] . dec_w + dec_b
// ---------------------------------------------------------------------------
__global__ __launch_bounds__(64)
void decode_kernel(const float* __restrict__ x, const float* __restrict__ dw,
                   const float* __restrict__ db, float* __restrict__ out) {
    const int b = blockIdx.x;
    const int lane = threadIdx.x;
    const float* r = x + ((size_t)b * Ss + (Ss - 1)) * Dd;
    float acc = 0.f;
    #pragma unroll
    for (int j = 0; j < 8; ++j) acc = fmaf(r[j*64 + lane], dw[j*64 + lane], acc);
    #pragma unroll
    for (int m = 1; m < 64; m <<= 1) acc += __shfl_xor(acc, m, 64);
    if (lane == 0) out[b] = acc + db[0];
}

// ---------------------------------------------------------------------------
extern "C" void kernel_launch(void* const* d_in, const int* in_sizes, int n_in,
                              void* d_out, int out_size, void* d_ws, size_t ws_size,
                              hipStream_t stream) {
    const float* src   = (const float*)d_in[0];
    const float* pe    = (const float*)d_in[1];
    const float* enc_w = (const float*)d_in[2];
    const float* enc_b = (const float*)d_in[3];
    const float* l1_w  = (const float*)d_in[4];
    const float* l1_b  = (const float*)d_in[5];
    const float* l2_w  = (const float*)d_in[6];
    const float* l2_b  = (const float*)d_in[7];
    const float* n1_g  = (const float*)d_in[8];
    const float* n1_b  = (const float*)d_in[9];
    const float* n2_g  = (const float*)d_in[10];
    const float* n2_b  = (const float*)d_in[11];
    const float* dec_w = (const float*)d_in[12];
    const float* dec_b = (const float*)d_in[13];
    float* out = (float*)d_out;

    // workspace (fixed 184MB): xA f32 64MB | xB f32 64MB | xBbf 32MB |
    //   w1bf 12MB | w2bf 12MB | hbf bf16 (remainder, chunk-adaptive; full
    //   single-pass needs 128MB -> 312MB total; smaller ws runs FFN in
    //   row-chunks of >=128 rows). Chunk count depends only on ws_size ->
    //   identical work every call (graph-capture safe).
    const size_t NTOK = (size_t)BS * Dd;          // 16.78M
    float*  xA   = (float*)d_ws;
    float*  xB   = xA + NTOK;
    ushort* xBbf = (ushort*)(xB + NTOK);
    ushort* w1bf = xBbf + NTOK;
    ushort* w2bf = w1bf + (size_t)Ll * FFf * Dd;
    ushort* hbf  = w2bf + (size_t)Ll * FFf * Dd;

    const size_t fixedBytes = (size_t)((char*)hbf - (char*)d_ws);
    size_t hBytes = ws_size > fixedBytes ? ws_size - fixedBytes : 0;
    int    chunkM = (int)(hBytes / ((size_t)FFf * sizeof(ushort)));
    if (chunkM > BS) chunkM = BS;
    chunkM &= ~127;                      // multiple of the GEMM tile height
    if (chunkM < 128) chunkM = 128;      // last resort: 512KB chunk

    const int wn4 = Ll * FFf * Dd / 4;
    convert_bf16<<<1024, 256, 0, stream>>>(l1_w, w1bf, wn4);
    convert_bf16<<<1024, 256, 0, stream>>>(l2_w, w2bf, wn4);

    encode_kernel<<<BS / 4, 256, 0, stream>>>(src, pe, enc_w, enc_b, xA);

    for (int i = 0; i < Ll; ++i) {
        attn_ln_kernel<<<BS / 4, 256, 0, stream>>>(
            xA, xB, xBbf, n1_g + i * Dd, n1_b + i * Dd);
        for (int m0 = 0; m0 < BS; m0 += chunkM) {
            int mh = (BS - m0) < chunkM ? (BS - m0) : chunkM;
            gemm_bf16<1, 1><<<dim3(FFf / 128, mh / 128), 256, 0, stream>>>(
                xBbf + (size_t)m0 * Dd, w1bf + (size_t)i * FFf * Dd,
                l1_b + i * FFf, hbf, mh, FFf, Dd);
            gemm_bf16<0, 0><<<dim3(Dd / 128, mh / 128), 256, 0, stream>>>(
                hbf, w2bf + (size_t)i * Dd * FFf, l2_b + i * Dd,
                xA + (size_t)m0 * Dd, mh, Dd, FFf);
        }
        add_ln_kernel<<<BS / 4, 256, 0, stream>>>(
            xB, xA, n2_g + i * Dd, n2_b + i * Dd);
    }

    decode_kernel<<<Bb, 64, 0, stream>>>(xA, dec_w, dec_b, out);
}

// Round 10
// 2009.741 us; speedup vs baseline: 4.9759x; 1.1293x over previous
//
#include <hip/hip_runtime.h>
#include <hip/hip_bf16.h>
#include <math.h>

// Problem constants
constexpr int Bb  = 16;
constexpr int Ss  = 2048;
constexpr int INd = 32;
constexpr int Dd  = 512;
constexpr int FFf = 2048;
constexpr int Ll  = 6;
constexpr int BS  = Bb * Ss;          // 32768 tokens
constexpr float EPSf = 1e-5f;

typedef __attribute__((ext_vector_type(8))) short short8;   // 8 bf16 (4 VGPRs)
typedef __attribute__((ext_vector_type(4))) float f32x4;

__device__ __forceinline__ ushort f2bf(float f) {
    uint u = __float_as_uint(f);
    uint r = (u + 0x7fffu + ((u >> 16) & 1u)) >> 16;        // round-nearest-even
    return (ushort)r;
}

// ---------------------------------------------------------------------------
// fp32 -> bf16 bulk convert (weights, once per launch)
// ---------------------------------------------------------------------------
__global__ __launch_bounds__(256)
void convert_bf16(const float* __restrict__ in, ushort* __restrict__ out, int n4) {
    int i = blockIdx.x * blockDim.x + threadIdx.x;
    int stride = gridDim.x * blockDim.x;
    for (; i < n4; i += stride) {
        float4 v = ((const float4*)in)[i];
        ushort4 o;
        o.x = f2bf(v.x); o.y = f2bf(v.y); o.z = f2bf(v.z); o.w = f2bf(v.w);
        ((ushort4*)out)[i] = o;
    }
}

// ---------------------------------------------------------------------------
// Encoder v2: register-resident enc_w. 2048 persistent blocks, 256 threads.
// Thread t owns output dims (2t, 2t+1): 64 weight floats in VGPRs, loaded
// ONCE per block (vs 64KB re-read per wave in v1 -> 2GB L2 traffic, 240us,
// VALUBusy 6.5%). Tokens grid-strided (16/block), src staged 8-at-a-time in
// LDS (broadcast), float2 coalesced stores.
// NOTE: reproduces the reference's pe[:x.shape[0]] broadcast (per-BATCH pe row)
// ---------------------------------------------------------------------------
__global__ __launch_bounds__(256)
void encode_kernel(const float* __restrict__ src, const float* __restrict__ pe,
                   const float* __restrict__ ew, const float* __restrict__ eb,
                   float* __restrict__ y) {
    __shared__ float s_src[8][32];
    const int tid = threadIdx.x;
    const int d0  = 2 * tid;                 // dims d0, d0+1
    float w0[32], w1[32];
    #pragma unroll
    for (int k = 0; k < 32; k += 4) {
        float4 a = *(const float4*)(ew + (size_t)d0 * INd + k);
        float4 b = *(const float4*)(ew + (size_t)(d0 + 1) * INd + k);
        w0[k] = a.x; w0[k+1] = a.y; w0[k+2] = a.z; w0[k+3] = a.w;
        w1[k] = b.x; w1[k+1] = b.y; w1[k+2] = b.z; w1[k+3] = b.w;
    }
    const float e0 = eb[d0], e1 = eb[d0 + 1];
    const float sqrtD = 22.62741699796952f;

    for (int t0 = 0; t0 < BS / 2048; t0 += 8) {
        __syncthreads();                     // protect s_src reuse
        {
            const int j = tid >> 5, e = tid & 31;
            const int tok = (int)blockIdx.x + (t0 + j) * 2048;
            s_src[j][e] = src[(size_t)tok * INd + e];
        }
        __syncthreads();
        #pragma unroll
        for (int j = 0; j < 8; ++j) {
            const int tok = (int)blockIdx.x + (t0 + j) * 2048;
            const int b   = tok >> 11;       // batch index
            float a0 = 0.f, a1 = 0.f;
            #pragma unroll
            for (int k = 0; k < 32; ++k) {
                const float sv = s_src[j][k];
                a0 = fmaf(sv, w0[k], a0);
                a1 = fmaf(sv, w1[k], a1);
            }
            const float2 pv = *(const float2*)(pe + (size_t)b * Dd + d0);
            float2 o;
            o.x = (a0 + e0) * sqrtD + pv.x;
            o.y = (a1 + e1) * sqrtD + pv.y;
            *(float2*)(y + (size_t)tok * Dd + d0) = o;
        }
    }
}

// ---------------------------------------------------------------------------
// Sparse window attention (W=3 -> 7 keys) + residual + LayerNorm, fused.
// One wave per token. Writes fp32 y (residual stream) AND bf16 ybf (GEMM1 A).
// ---------------------------------------------------------------------------
__global__ __launch_bounds__(256)
void attn_ln_kernel(const float* __restrict__ x, float* __restrict__ y,
                    ushort* __restrict__ ybf,
                    const float* __restrict__ g, const float* __restrict__ bb) {
    const int wv   = threadIdx.x >> 6;
    const int lane = threadIdx.x & 63;
    const int wid  = blockIdx.x * 4 + wv;
    const int b    = wid >> 11;
    const int s    = wid & (Ss - 1);
    const float* base = x + (size_t)b * Ss * Dd;

    float rows[7][8];
    #pragma unroll
    for (int o = 0; o < 7; ++o) {
        int sp = s + o - 3;
        int sc = sp < 0 ? 0 : (sp > Ss - 1 ? Ss - 1 : sp);
        const float* r = base + (size_t)sc * Dd;
        float4 v0 = *(const float4*)(r + lane * 4);
        float4 v1 = *(const float4*)(r + 256 + lane * 4);
        rows[o][0] = v0.x; rows[o][1] = v0.y; rows[o][2] = v0.z; rows[o][3] = v0.w;
        rows[o][4] = v1.x; rows[o][5] = v1.y; rows[o][6] = v1.z; rows[o][7] = v1.w;
    }

    const float scale = 0.04419417382415922f;   // 1/sqrt(512)
    float score[7];
    #pragma unroll
    for (int o = 0; o < 7; ++o) {
        float p = 0.f;
        #pragma unroll
        for (int j = 0; j < 8; ++j) p = fmaf(rows[3][j], rows[o][j], p);
        #pragma unroll
        for (int m = 1; m < 64; m <<= 1) p += __shfl_xor(p, m, 64);
        int sp = s + o - 3;
        score[o] = (sp >= 0 && sp < Ss) ? p * scale : -1e9f;
    }
    float mx = score[0];
    #pragma unroll
    for (int o = 1; o < 7; ++o) mx = fmaxf(mx, score[o]);
    float w[7], wsum = 0.f;
    #pragma unroll
    for (int o = 0; o < 7; ++o) { w[o] = __expf(score[o] - mx); wsum += w[o]; }
    const float inv = 1.f / wsum;
    #pragma unroll
    for (int o = 0; o < 7; ++o) w[o] *= inv;

    float r2[8];
    #pragma unroll
    for (int j = 0; j < 8; ++j) {
        float acc = rows[3][j];                 // residual (pre-LN x)
        #pragma unroll
        for (int o = 0; o < 7; ++o) acc = fmaf(w[o], rows[o][j], acc);
        r2[j] = acc;
    }

    // LayerNorm over 512
    float sm = 0.f, sq = 0.f;
    #pragma unroll
    for (int j = 0; j < 8; ++j) { sm += r2[j]; sq = fmaf(r2[j], r2[j], sq); }
    #pragma unroll
    for (int m = 1; m < 64; m <<= 1) {
        sm += __shfl_xor(sm, m, 64);
        sq += __shfl_xor(sq, m, 64);
    }
    const float mu   = sm * (1.f / Dd);
    const float var  = sq * (1.f / Dd) - mu * mu;
    const float rstd = rsqrtf(var + EPSf);

    const size_t ob = (size_t)wid * Dd;
    float4 g0 = *(const float4*)(g  + lane * 4);
    float4 b0 = *(const float4*)(bb + lane * 4);
    float4 g1 = *(const float4*)(g  + 256 + lane * 4);
    float4 b1 = *(const float4*)(bb + 256 + lane * 4);
    float4 o0, o1;
    o0.x = (r2[0] - mu) * rstd * g0.x + b0.x;
    o0.y = (r2[1] - mu) * rstd * g0.y + b0.y;
    o0.z = (r2[2] - mu) * rstd * g0.z + b0.z;
    o0.w = (r2[3] - mu) * rstd * g0.w + b0.w;
    o1.x = (r2[4] - mu) * rstd * g1.x + b1.x;
    o1.y = (r2[5] - mu) * rstd * g1.y + b1.y;
    o1.z = (r2[6] - mu) * rstd * g1.z + b1.z;
    o1.w = (r2[7] - mu) * rstd * g1.w + b1.w;
    *(float4*)(y + ob + lane * 4)       = o0;
    *(float4*)(y + ob + 256 + lane * 4) = o1;

    ushort4 q0, q1;
    q0.x = f2bf(o0.x); q0.y = f2bf(o0.y); q0.z = f2bf(o0.z); q0.w = f2bf(o0.w);
    q1.x = f2bf(o1.x); q1.y = f2bf(o1.y); q1.z = f2bf(o1.z); q1.w = f2bf(o1.w);
    *(ushort4*)(ybf + ob + lane * 4)       = q0;
    *(ushort4*)(ybf + ob + 256 + lane * 4) = q1;
}

// ---------------------------------------------------------------------------
// residual add + LayerNorm:  f <- LN(xres + f) * g + b   (in-place on f)
// ---------------------------------------------------------------------------
__global__ __launch_bounds__(256)
void add_ln_kernel(const float* __restrict__ xres, float* __restrict__ f,
                   const float* __restrict__ g, const float* __restrict__ bb) {
    const int wv   = threadIdx.x >> 6;
    const int lane = threadIdx.x & 63;
    const int wid  = blockIdx.x * 4 + wv;
    const size_t ob = (size_t)wid * Dd;

    float4 a0 = *(const float4*)(xres + ob + lane * 4);
    float4 f0 = *(const float4*)(f    + ob + lane * 4);
    float4 a1 = *(const float4*)(xres + ob + 256 + lane * 4);
    float4 f1 = *(const float4*)(f    + ob + 256 + lane * 4);
    float r2[8];
    r2[0] = a0.x + f0.x; r2[1] = a0.y + f0.y; r2[2] = a0.z + f0.z; r2[3] = a0.w + f0.w;
    r2[4] = a1.x + f1.x; r2[5] = a1.y + f1.y; r2[6] = a1.z + f1.z; r2[7] = a1.w + f1.w;

    float sm = 0.f, sq = 0.f;
    #pragma unroll
    for (int j = 0; j < 8; ++j) { sm += r2[j]; sq = fmaf(r2[j], r2[j], sq); }
    #pragma unroll
    for (int m = 1; m < 64; m <<= 1) {
        sm += __shfl_xor(sm, m, 64);
        sq += __shfl_xor(sq, m, 64);
    }
    const float mu   = sm * (1.f / Dd);
    const float var  = sq * (1.f / Dd) - mu * mu;
    const float rstd = rsqrtf(var + EPSf);

    float4 g0 = *(const float4*)(g  + lane * 4);
    float4 b0 = *(const float4*)(bb + lane * 4);
    float4 g1 = *(const float4*)(g  + 256 + lane * 4);
    float4 b1 = *(const float4*)(bb + 256 + lane * 4);
    float4 o0, o1;
    o0.x = (r2[0] - mu) * rstd * g0.x + b0.x;
    o0.y = (r2[1] - mu) * rstd * g0.y + b0.y;
    o0.z = (r2[2] - mu) * rstd * g0.z + b0.z;
    o0.w = (r2[3] - mu) * rstd * g0.w + b0.w;
    o1.x = (r2[4] - mu) * rstd * g1.x + b1.x;
    o1.y = (r2[5] - mu) * rstd * g1.y + b1.y;
    o1.z = (r2[6] - mu) * rstd * g1.z + b1.z;
    o1.w = (r2[7] - mu) * rstd * g1.w + b1.w;
    *(float4*)(f + ob + lane * 4)       = o0;
    *(float4*)(f + ob + 256 + lane * 4) = o1;
}

// ---------------------------------------------------------------------------
// bf16 MFMA NT GEMM (m97 structure): C[m,n] = sum_k A[m,k]*B[n,k] + bias[n]
// A: MxK bf16 row-major, B: NxK bf16 row-major. 128x128 tile, BK=32.
// 4 waves, each computes a 64x64 quadrant as 4x4 fragments of 16x16x32 MFMA.
// Staging via global_load_lds width=16 (wave-uniform LDS base + lane*16).
// XCD-aware bijective block swizzle (m204): contiguous tile ranges per XCD
// so blocks sharing an A-panel hit the same XCD L2.
// Epilogue: +bias, optional ReLU, output fp32 or bf16.
// ---------------------------------------------------------------------------
template<int RELU, int BF16OUT>
__global__ __launch_bounds__(256)
void gemm_bf16(const ushort* __restrict__ A, const ushort* __restrict__ B,
               const float* __restrict__ bias, void* __restrict__ Cout,
               int M, int N, int K) {
    __shared__ ushort As[128 * 32];          // [row][k] bf16, 8KB
    __shared__ ushort Bs[128 * 32];
    const int tid  = threadIdx.x;
    const int wid  = tid >> 6;
    const int lane = tid & 63;
    const int wr   = wid >> 1;               // wave quadrant row (0/1)
    const int wc   = wid & 1;                // wave quadrant col (0/1)

    // ---- XCD-aware bijective swizzle (nwg may not be divisible by 8) ----
    const int nwg  = (int)(gridDim.x * gridDim.y);
    const int orig = (int)(blockIdx.y * gridDim.x + blockIdx.x);
    const int q    = nwg >> 3, r = nwg & 7;
    const int xcd  = orig & 7, seq = orig >> 3;
    const int swz  = (xcd < r ? xcd * (q + 1) : r * (q + 1) + (xcd - r) * q) + seq;
    const int bxT  = swz % (int)gridDim.x;   // N-tile (fast dim)
    const int byT  = swz / (int)gridDim.x;   // M-tile
    const size_t bm = (size_t)byT * 128;
    const size_t bn = (size_t)bxT * 128;

    // staging sources: wave w stages rows [w*32, w*32+32) of the 128-row tile
    // each GLDS covers 16 rows; lane l -> row += (l>>2), k = (l&3)*8
    const ushort* gA0 = A + (bm + wid * 32 + (lane >> 2)) * (size_t)K + (lane & 3) * 8;
    const ushort* gA1 = gA0 + (size_t)16 * K;
    const ushort* gB0 = B + (bn + wid * 32 + (lane >> 2)) * (size_t)K + (lane & 3) * 8;
    const ushort* gB1 = gB0 + (size_t)16 * K;
    ushort* lA0 = &As[wid * 1024];           // (w*32 rows)*32 k
    ushort* lA1 = lA0 + 512;                 // +16 rows
    ushort* lB0 = &Bs[wid * 1024];
    ushort* lB1 = lB0 + 512;

    // fragment read bases: row = quadrant*64 + mt*16 + (lane&15), kg = lane>>4
    const ushort* aPtr = &As[(wr * 64 + (lane & 15)) * 32 + (lane >> 4) * 8];
    const ushort* bPtr = &Bs[(wc * 64 + (lane & 15)) * 32 + (lane >> 4) * 8];

    f32x4 acc[4][4];
    #pragma unroll
    for (int i = 0; i < 4; ++i)
        #pragma unroll
        for (int j = 0; j < 4; ++j) acc[i][j] = (f32x4){0.f, 0.f, 0.f, 0.f};

    #define GLDS(gp, lp) __builtin_amdgcn_global_load_lds( \
        (const __attribute__((address_space(1))) void*)(gp), \
        (__attribute__((address_space(3))) void*)(lp), 16, 0, 0)

    for (int k0 = 0; k0 < K; k0 += 32) {
        GLDS(gA0 + k0, lA0);
        GLDS(gA1 + k0, lA1);
        GLDS(gB0 + k0, lB0);
        GLDS(gB1 + k0, lB1);
        __syncthreads();
        short8 af[4], bf_[4];
        #pragma unroll
        for (int mt = 0; mt < 4; ++mt) af[mt]  = *(const short8*)(aPtr + mt * 512);
        #pragma unroll
        for (int nt = 0; nt < 4; ++nt) bf_[nt] = *(const short8*)(bPtr + nt * 512);
        #pragma unroll
        for (int mt = 0; mt < 4; ++mt)
            #pragma unroll
            for (int nt = 0; nt < 4; ++nt)
                acc[mt][nt] = __builtin_amdgcn_mfma_f32_16x16x32_bf16(
                    af[mt], bf_[nt], acc[mt][nt], 0, 0, 0);
        __syncthreads();
    }
    #undef GLDS

    // epilogue: C row = bm + wr*64 + mt*16 + (lane>>4)*4 + r ; col = bn + wc*64 + nt*16 + (lane&15)
    float* Cf  = (float*)Cout;
    ushort* Cb = (ushort*)Cout;
    #pragma unroll
    for (int nt = 0; nt < 4; ++nt) {
        const int cn = (int)bn + wc * 64 + nt * 16 + (lane & 15);
        const float bv = bias[cn];
        #pragma unroll
        for (int mt = 0; mt < 4; ++mt) {
            const size_t rowb = bm + wr * 64 + mt * 16 + (lane >> 4) * 4;
            #pragma unroll
            for (int rr = 0; rr < 4; ++rr) {
                float v = acc[mt][nt][rr] + bv;
                if (RELU) v = fmaxf(v, 0.f);
                if (BF16OUT) Cb[(rowb + rr) * (size_t)N + cn] = f2bf(v);
                else         Cf[(rowb + rr) * (size_t)N + cn] = v;
            }
        }
    }
}

// ---------------------------------------------------------------------------
// Decoder: out[b] = x[b, S-1, :] . dec_w + dec_b
// ---------------------------------------------------------------------------
__global__ __launch_bounds__(64)
void decode_kernel(const float* __restrict__ x, const float* __restrict__ dw,
                   const float* __restrict__ db, float* __restrict__ out) {
    const int b = blockIdx.x;
    const int lane = threadIdx.x;
    const float* r = x + ((size_t)b * Ss + (Ss - 1)) * Dd;
    float acc = 0.f;
    #pragma unroll
    for (int j = 0; j < 8; ++j) acc = fmaf(r[j*64 + lane], dw[j*64 + lane], acc);
    #pragma unroll
    for (int m = 1; m < 64; m <<= 1) acc += __shfl_xor(acc, m, 64);
    if (lane == 0) out[b] = acc + db[0];
}

// ---------------------------------------------------------------------------
extern "C" void kernel_launch(void* const* d_in, const int* in_sizes, int n_in,
                              void* d_out, int out_size, void* d_ws, size_t ws_size,
                              hipStream_t stream) {
    const float* src   = (const float*)d_in[0];
    const float* pe    = (const float*)d_in[1];
    const float* enc_w = (const float*)d_in[2];
    const float* enc_b = (const float*)d_in[3];
    const float* l1_w  = (const float*)d_in[4];
    const float* l1_b  = (const float*)d_in[5];
    const float* l2_w  = (const float*)d_in[6];
    const float* l2_b  = (const float*)d_in[7];
    const float* n1_g  = (const float*)d_in[8];
    const float* n1_b  = (const float*)d_in[9];
    const float* n2_g  = (const float*)d_in[10];
    const float* n2_b  = (const float*)d_in[11];
    const float* dec_w = (const float*)d_in[12];
    const float* dec_b = (const float*)d_in[13];
    float* out = (float*)d_out;

    // workspace (fixed 184MB): xA f32 64MB | xB f32 64MB | xBbf 32MB |
    //   w1bf 12MB | w2bf 12MB | hbf bf16 (remainder, chunk-adaptive; full
    //   single-pass needs 128MB -> 312MB total; smaller ws runs FFN in
    //   row-chunks of >=128 rows). Chunk count depends only on ws_size ->
    //   identical work every call (graph-capture safe).
    const size_t NTOK = (size_t)BS * Dd;          // 16.78M
    float*  xA   = (float*)d_ws;
    float*  xB   = xA + NTOK;
    ushort* xBbf = (ushort*)(xB + NTOK);
    ushort* w1bf = xBbf + NTOK;
    ushort* w2bf = w1bf + (size_t)Ll * FFf * Dd;
    ushort* hbf  = w2bf + (size_t)Ll * FFf * Dd;

    const size_t fixedBytes = (size_t)((char*)hbf - (char*)d_ws);
    size_t hBytes = ws_size > fixedBytes ? ws_size - fixedBytes : 0;
    int    chunkM = (int)(hBytes / ((size_t)FFf * sizeof(ushort)));
    if (chunkM > BS) chunkM = BS;
    chunkM &= ~127;                      // multiple of the GEMM tile height
    if (chunkM < 128) chunkM = 128;      // last resort: 512KB chunk

    const int wn4 = Ll * FFf * Dd / 4;
    convert_bf16<<<1024, 256, 0, stream>>>(l1_w, w1bf, wn4);
    convert_bf16<<<1024, 256, 0, stream>>>(l2_w, w2bf, wn4);

    encode_kernel<<<2048, 256, 0, stream>>>(src, pe, enc_w, enc_b, xA);

    for (int i = 0; i < Ll; ++i) {
        attn_ln_kernel<<<BS / 4, 256, 0, stream>>>(
            xA, xB, xBbf, n1_g + i * Dd, n1_b + i * Dd);
        for (int m0 = 0; m0 < BS; m0 += chunkM) {
            int mh = (BS - m0) < chunkM ? (BS - m0) : chunkM;
            gemm_bf16<1, 1><<<dim3(FFf / 128, mh / 128), 256, 0, stream>>>(
                xBbf + (size_t)m0 * Dd, w1bf + (size_t)i * FFf * Dd,
                l1_b + i * FFf, hbf, mh, FFf, Dd);
            gemm_bf16<0, 0><<<dim3(Dd / 128, mh / 128), 256, 0, stream>>>(
                hbf, w2bf + (size_t)i * Dd * FFf, l2_b + i * Dd,
                xA + (size_t)m0 * Dd, mh, Dd, FFf);
        }
        add_ln_kernel<<<BS / 4, 256, 0, stream>>>(
            xB, xA, n2_g + i * Dd, n2_b + i * Dd);
    }

    decode_kernel<<<Bb, 64, 0, stream>>>(xA, dec_w, dec_b, out);
}